// Round 1
// baseline (320.338 us; speedup 1.0000x reference)
//
#include <hip/hip_runtime.h>
#include <math.h>

typedef __attribute__((ext_vector_type(4))) float f32x4;
typedef __attribute__((ext_vector_type(8))) short s16x8;
typedef __attribute__((ext_vector_type(8))) __bf16 bf16x8v;

static constexpr int WG_OFF = 0;
static constexpr int WL_OFF = 163840;
static constexpr int WQ_OFF = 327680;
static constexpr int WK_OFF = 393216;
static constexpr int WV_OFF = 458752;
static constexpr int WO_OFF = 524288;
static constexpr int W1_OFF = 589824;
static constexpr int W_TOTAL = 622592;

__device__ __forceinline__ unsigned short f2bf(float f) {
  unsigned u = __builtin_bit_cast(unsigned, f);
  u += 0x7FFFu + ((u >> 16) & 1u);
  return (unsigned short)(u >> 16);
}
__device__ __forceinline__ float bf2f(unsigned short h) {
  unsigned u = ((unsigned)h) << 16;
  return __builtin_bit_cast(float, u);
}
__device__ __forceinline__ f32x4 mfma16(s16x8 a, s16x8 b, f32x4 c) {
  return __builtin_amdgcn_mfma_f32_16x16x32_bf16(
      __builtin_bit_cast(bf16x8v, a), __builtin_bit_cast(bf16x8v, b), c, 0, 0, 0);
}
__device__ __forceinline__ f32x4 fzero4() {
  f32x4 v; v[0] = 0.f; v[1] = 0.f; v[2] = 0.f; v[3] = 0.f; return v;
}
__device__ __forceinline__ s16x8 pack8(float4 x, float4 y) {
  s16x8 r;
  r[0] = (short)f2bf(x.x); r[1] = (short)f2bf(x.y);
  r[2] = (short)f2bf(x.z); r[3] = (short)f2bf(x.w);
  r[4] = (short)f2bf(y.x); r[5] = (short)f2bf(y.y);
  r[6] = (short)f2bf(y.z); r[7] = (short)f2bf(y.w);
  return r;
}

// Swizzled bf16 LDS tile accessors: tile is [128 rows][256 cols] bf16, 512 B/row.
// byte ^= ((row&7)<<4) spreads the 16B column-slots across banks.
__device__ __forceinline__ void stC(unsigned short* s, int row, int col, float v) {
  int byte = row * 512 + ((col * 2) ^ ((row & 7) << 4));
  *(unsigned short*)((char*)s + byte) = f2bf(v);
}
__device__ __forceinline__ float ldC(const unsigned short* s, int row, int col) {
  int byte = row * 512 + ((col * 2) ^ ((row & 7) << 4));
  return bf2f(*(const unsigned short*)((const char*)s + byte));
}

__device__ __forceinline__ void stage_w(const unsigned short* __restrict__ src,
                                        unsigned short* dst, int chunks, int tid) {
  const s16x8* s = (const s16x8*)src;
  s16x8* d = (s16x8*)dst;
  for (int c = tid; c < chunks; c += 512) d[c] = s[c];
}

template <int N>
__device__ __forceinline__ void red16(float* v) {
#pragma unroll
  for (int m = 1; m < 16; m <<= 1) {
#pragma unroll
    for (int i = 0; i < N; ++i) v[i] += __shfl_xor(v[i], m);
  }
}

// Phase 1: C[128,256] = A[128rows,640]fp32 @ W(frag-layout bf16) + bias -> swizzled LDS tile
__device__ __forceinline__ void proj640(const float* __restrict__ A,
                                        const unsigned short* __restrict__ wsW,
                                        const float* __restrict__ bias,
                                        unsigned short* sDst, unsigned short* sWst,
                                        int blk, int tid) {
  const int lane = tid & 63, l15 = lane & 15, kg4 = lane >> 4;
  const int w = tid >> 6, wr = w >> 1, wc = w & 1;
  f32x4 acc[2][8];
#pragma unroll
  for (int m = 0; m < 2; ++m)
#pragma unroll
    for (int n = 0; n < 8; ++n) acc[m][n] = fzero4();
  for (int kt = 0; kt < 20; ++kt) {
    __syncthreads();
    stage_w(wsW + kt * 8192, sWst, 1024, tid);
    __syncthreads();
    s16x8 a[2];
#pragma unroll
    for (int m = 0; m < 2; ++m) {
      const float* ap =
          A + (size_t)(blk * 128 + wr * 32 + m * 16 + l15) * 640 + kt * 32 + kg4 * 8;
      float4 f0 = *(const float4*)ap;
      float4 f1 = *(const float4*)(ap + 4);
      a[m] = pack8(f0, f1);
    }
#pragma unroll
    for (int n = 0; n < 8; ++n) {
      s16x8 b = *(const s16x8*)(sWst + ((wc * 8 + n) * 64 + lane) * 8);
#pragma unroll
      for (int m = 0; m < 2; ++m) acc[m][n] = mfma16(a[m], b, acc[m][n]);
    }
  }
#pragma unroll
  for (int n = 0; n < 8; ++n) {
    const int col = wc * 128 + n * 16 + l15;
    const float bv = bias[col];
#pragma unroll
    for (int m = 0; m < 2; ++m)
#pragma unroll
      for (int r = 0; r < 4; ++r)
        stC(sDst, wr * 32 + m * 16 + kg4 * 4 + r, col, acc[m][n][r] + bv);
  }
}

// K=256 GEMM: per-wave 16 rows x NF*16 cols, A from swizzled LDS tile.
template <int NF>
__device__ __forceinline__ void gemmA(const unsigned short* sA,
                                      const unsigned short* __restrict__ wsW,
                                      unsigned short* sWst, f32x4* acc, int wrow, int tid) {
  const int lane = tid & 63, l15 = lane & 15, kg4 = lane >> 4;
  const int row = wrow + l15;
  for (int kt = 0; kt < 8; ++kt) {
    __syncthreads();
    stage_w(wsW + kt * NF * 512, sWst, NF * 64, tid);
    __syncthreads();
    const int off = (kt * 64 + kg4 * 16) ^ ((row & 7) << 4);
    s16x8 a = *(const s16x8*)((const char*)sA + row * 512 + off);
#pragma unroll
    for (int n = 0; n < NF; ++n) {
      s16x8 b = *(const s16x8*)(sWst + (n * 64 + lane) * 8);
      acc[n] = mfma16(a, b, acc[n]);
    }
  }
}

template <int NF>
__device__ __forceinline__ void gemmDual(const unsigned short* sA0, const unsigned short* sA1,
                                         const unsigned short* __restrict__ wsW,
                                         unsigned short* sWst, f32x4* acc0, f32x4* acc1,
                                         int wrow, int tid) {
  const int lane = tid & 63, l15 = lane & 15, kg4 = lane >> 4;
  const int row = wrow + l15;
  for (int kt = 0; kt < 8; ++kt) {
    __syncthreads();
    stage_w(wsW + kt * NF * 512, sWst, NF * 64, tid);
    __syncthreads();
    const int off = (kt * 64 + kg4 * 16) ^ ((row & 7) << 4);
    s16x8 a0 = *(const s16x8*)((const char*)sA0 + row * 512 + off);
    s16x8 a1 = *(const s16x8*)((const char*)sA1 + row * 512 + off);
#pragma unroll
    for (int n = 0; n < NF; ++n) {
      s16x8 b = *(const s16x8*)(sWst + (n * 64 + lane) * 8);
      acc0[n] = mfma16(a0, b, acc0[n]);
      acc1[n] = mfma16(a1, b, acc1[n]);
    }
  }
}

__global__ void convert_w(const float* __restrict__ Wg, const float* __restrict__ Wl,
                          const float* __restrict__ Win, const float* __restrict__ Wout,
                          const float* __restrict__ W1, unsigned short* __restrict__ ws) {
  const int tid = blockIdx.x * 256 + threadIdx.x;
  if (tid >= W_TOTAL) return;
  const float* src;
  int stride, coloff, base, lognf;
  if (tid < WL_OFF)      { src = Wg;   stride = 256; coloff = 0;   base = WG_OFF; lognf = 4; }
  else if (tid < WQ_OFF) { src = Wl;   stride = 256; coloff = 0;   base = WL_OFF; lognf = 4; }
  else if (tid < WK_OFF) { src = Win;  stride = 768; coloff = 0;   base = WQ_OFF; lognf = 4; }
  else if (tid < WV_OFF) { src = Win;  stride = 768; coloff = 256; base = WK_OFF; lognf = 4; }
  else if (tid < WO_OFF) { src = Win;  stride = 768; coloff = 512; base = WV_OFF; lognf = 4; }
  else if (tid < W1_OFF) { src = Wout; stride = 256; coloff = 0;   base = WO_OFF; lognf = 4; }
  else                   { src = W1;   stride = 128; coloff = 0;   base = W1_OFF; lognf = 3; }
  const int idx = tid - base;
  const int j = idx & 7;
  const int lane = (idx >> 3) & 63;
  const int fl = idx >> 9;
  const int n = fl & ((1 << lognf) - 1);
  const int kt = fl >> lognf;
  const int k = kt * 32 + (lane >> 4) * 8 + j;
  const int col = coloff + n * 16 + (lane & 15);
  ws[tid] = f2bf(src[k * stride + col]);
}

__global__ __launch_bounds__(512, 2) void dca_fused(
    const float* __restrict__ gdiff, const float* __restrict__ ldiff,
    const float* __restrict__ bg, const float* __restrict__ bl,
    const float* __restrict__ bin, const float* __restrict__ bout,
    const float* __restrict__ gamma, const float* __restrict__ beta,
    const float* __restrict__ b1, const float* __restrict__ W2,
    const float* __restrict__ b2, const unsigned short* __restrict__ wsw,
    float* __restrict__ out) {
  __shared__ unsigned short sG[32768];  // g tile [128][256] bf16, swizzled
  __shared__ unsigned short sL[32768];  // l tile, later ctx, later y
  __shared__ unsigned short sW[8192];   // 16KB weight staging
  const int tid = threadIdx.x;
  const int blk = blockIdx.x;
  const int lane = tid & 63, l15 = lane & 15, kg4 = lane >> 4;
  const int w = tid >> 6;
  const int wrow = w * 16;

  // ---- phase 1: g = global @ Wg + bg ; l = local @ Wl + bl
  proj640(gdiff, wsw + WG_OFF, bg, sG, sW, blk, tid);
  proj640(ldiff, wsw + WL_OFF, bl, sL, sW, blk, tid);

  // ---- phase 2: q
  f32x4 qa[16];
#pragma unroll
  for (int n = 0; n < 16; ++n) qa[n] = fzero4();
  gemmA<16>(sG, wsw + WQ_OFF, sW, qa, wrow, tid);
#pragma unroll
  for (int n = 0; n < 16; ++n) {
    const float bv = bin[n * 16 + l15];
#pragma unroll
    for (int r = 0; r < 4; ++r) qa[n][r] += bv;
  }

  // ---- kg, kl
  f32x4 kga[16], kla[16];
#pragma unroll
  for (int n = 0; n < 16; ++n) { kga[n] = fzero4(); kla[n] = fzero4(); }
  gemmDual<16>(sG, sL, wsw + WK_OFF, sW, kga, kla, wrow, tid);
#pragma unroll
  for (int n = 0; n < 16; ++n) {
    const float bv = bin[256 + n * 16 + l15];
#pragma unroll
    for (int r = 0; r < 4; ++r) { kga[n][r] += bv; kla[n][r] += bv; }
  }

  // ---- scores (per head h, per owned row r), reduce over 16 lanes (cols)
  float s01[32];
#pragma unroll
  for (int h = 0; h < 4; ++h)
#pragma unroll
    for (int r = 0; r < 4; ++r) {
      float t0 = 0.f, t1 = 0.f;
#pragma unroll
      for (int j = 0; j < 4; ++j) {
        t0 += qa[h * 4 + j][r] * kga[h * 4 + j][r];
        t1 += qa[h * 4 + j][r] * kla[h * 4 + j][r];
      }
      s01[h * 4 + r] = t0;
      s01[16 + h * 4 + r] = t1;
    }
  red16<32>(s01);
  float a0[16], a1[16];
#pragma unroll
  for (int i = 0; i < 16; ++i) {
    const float d = (s01[i] - s01[16 + i]) * 0.125f;  // (s0-s1)*scale
    const float t = 1.0f / (1.0f + expf(d));          // softmax weight of s1
    a1[i] = t;
    a0[i] = 1.0f - t;
  }

  // ---- vg, vl -> ctx (v bias folded: a0+a1 = 1)
  f32x4 vga[16], vla[16];
#pragma unroll
  for (int n = 0; n < 16; ++n) { vga[n] = fzero4(); vla[n] = fzero4(); }
  gemmDual<16>(sG, sL, wsw + WV_OFF, sW, vga, vla, wrow, tid);
#pragma unroll
  for (int n = 0; n < 16; ++n) {
    const float bv = bin[512 + n * 16 + l15];
    const int h = n >> 2;
#pragma unroll
    for (int r = 0; r < 4; ++r)
      vga[n][r] = a0[h * 4 + r] * vga[n][r] + a1[h * 4 + r] * vla[n][r] + bv;
  }
  // store ctx into sL (each wave owns its 16 rows; its own sL reads are done)
#pragma unroll
  for (int n = 0; n < 16; ++n)
#pragma unroll
    for (int r = 0; r < 4; ++r)
      stC(sL, wrow + kg4 * 4 + r, n * 16 + l15, vga[n][r]);

  // ---- phase 3: attended = ctx @ W_out + b_out; x = g + attended; LayerNorm
  f32x4 at[16];
#pragma unroll
  for (int n = 0; n < 16; ++n) at[n] = fzero4();
  gemmA<16>(sL, wsw + WO_OFF, sW, at, wrow, tid);
  float sm[4] = {0.f, 0.f, 0.f, 0.f}, sq[4] = {0.f, 0.f, 0.f, 0.f};
#pragma unroll
  for (int n = 0; n < 16; ++n) {
    const float bv = bout[n * 16 + l15];
#pragma unroll
    for (int r = 0; r < 4; ++r) {
      const float x = at[n][r] + bv + ldC(sG, wrow + kg4 * 4 + r, n * 16 + l15);
      at[n][r] = x;
      sm[r] += x;
      sq[r] += x * x;
    }
  }
  red16<4>(sm);
  red16<4>(sq);
  float mu[4], rs[4];
#pragma unroll
  for (int r = 0; r < 4; ++r) {
    mu[r] = sm[r] * (1.0f / 256.0f);
    const float var = sq[r] * (1.0f / 256.0f) - mu[r] * mu[r];
    rs[r] = rsqrtf(var + 1e-5f);
  }
#pragma unroll
  for (int n = 0; n < 16; ++n) {
    const float ga = gamma[n * 16 + l15];
    const float be = beta[n * 16 + l15];
#pragma unroll
    for (int r = 0; r < 4; ++r) {
      const float y = (at[n][r] - mu[r]) * rs[r] * ga + be;
      stC(sL, wrow + kg4 * 4 + r, n * 16 + l15, y);
    }
  }

  // ---- phase 4: MLP head
  f32x4 ha[8];
#pragma unroll
  for (int n = 0; n < 8; ++n) ha[n] = fzero4();
  gemmA<8>(sL, wsw + W1_OFF, sW, ha, wrow, tid);
  float o[4] = {0.f, 0.f, 0.f, 0.f};
#pragma unroll
  for (int n = 0; n < 8; ++n) {
    const float bv = b1[n * 16 + l15];
    const float w2 = W2[n * 16 + l15];
#pragma unroll
    for (int r = 0; r < 4; ++r) {
      float hv = ha[n][r] + bv;
      hv = 0.5f * hv * (1.0f + erff(hv * 0.70710678118654752f));  // exact GELU
      o[r] += hv * w2;
    }
  }
  red16<4>(o);
  if (l15 == 0) {
    const float bb = b2[0];
#pragma unroll
    for (int r = 0; r < 4; ++r)
      out[blk * 128 + wrow + kg4 * 4 + r] = o[r] + bb;
  }
}

extern "C" void kernel_launch(void* const* d_in, const int* in_sizes, int n_in,
                              void* d_out, int out_size, void* d_ws, size_t ws_size,
                              hipStream_t stream) {
  (void)in_sizes; (void)n_in; (void)out_size; (void)ws_size;
  const float* gdiff = (const float*)d_in[0];
  const float* ldiff = (const float*)d_in[1];
  const float* Wg    = (const float*)d_in[2];
  const float* bg    = (const float*)d_in[3];
  const float* Wl    = (const float*)d_in[4];
  const float* bl    = (const float*)d_in[5];
  const float* Win   = (const float*)d_in[6];
  const float* bin   = (const float*)d_in[7];
  const float* Wout  = (const float*)d_in[8];
  const float* bout  = (const float*)d_in[9];
  const float* gamma = (const float*)d_in[10];
  const float* beta  = (const float*)d_in[11];
  const float* W1    = (const float*)d_in[12];
  const float* b1    = (const float*)d_in[13];
  const float* W2    = (const float*)d_in[14];
  const float* b2    = (const float*)d_in[15];
  unsigned short* ws = (unsigned short*)d_ws;
  float* out = (float*)d_out;

  convert_w<<<dim3((W_TOTAL + 255) / 256), dim3(256), 0, stream>>>(Wg, Wl, Win, Wout, W1, ws);
  dca_fused<<<dim3(512), dim3(512), 0, stream>>>(gdiff, ldiff, bg, bl, bin, bout, gamma,
                                                 beta, b1, W2, b2,
                                                 (const unsigned short*)ws, out);
}